// Round 6
// baseline (1121.603 us; speedup 1.0000x reference)
//
#include <hip/hip_runtime.h>
#include <math.h>
#include <float.h>

#define B_   16
#define N_   4096
#define CIN  3
#define COUT 64
#define KNN  20
#define EPS_ 1e-5

// ---------------------------------------------------------------------------
// Workspace layout:
//   [0,   216): double stats[27]    (Sum e[6], Sum e e^T upper-tri[21])
//   [256, 768): float scale[64], shift[64]
//   [1024, 1024 + B*N*KNN*4): int idx[B*N*KNN]           (5242880 B)
//   [5243904, +B*N*4): int perm[B*N]  (Morton row order)  (262144 B)
// ---------------------------------------------------------------------------

__device__ __forceinline__ unsigned expand10(unsigned v) {
    v = (v | (v << 16)) & 0x030000FFu;
    v = (v | (v << 8))  & 0x0300F00Fu;
    v = (v | (v << 4))  & 0x030C30C3u;
    v = (v | (v << 2))  & 0x09249249u;
    return v;
}
__device__ __forceinline__ unsigned quant10(float v) {
    int q = (int)((v + 4.0f) * 128.0f);
    return (unsigned)min(1023, max(0, q));
}

// ===========================================================================
// Kernel 0: per-batch Morton COUNTING sort (1024 buckets = top 10 morton
// bits). PERFORMANCE ONLY: any permutation is correctness-neutral.
// ===========================================================================
__global__ __launch_bounds__(1024) void morton_bucket_kernel(
    const float* __restrict__ x, int* __restrict__ perm)
{
    __shared__ int hist[1024];
    __shared__ int scanbuf[1024];
    __shared__ int offs[1024];
    const int b = blockIdx.x, tid = threadIdx.x;
    const float* xb = x + (size_t)b * N_ * CIN;

    hist[tid] = 0;
    __syncthreads();

    int keys[4];
#pragma unroll
    for (int i = 0; i < 4; ++i) {
        int p = tid + i * 1024;
        float v0 = xb[p * 3 + 0], v1 = xb[p * 3 + 1], v2 = xb[p * 3 + 2];
        unsigned m = (expand10(quant10(v0)) << 2) |
                     (expand10(quant10(v1)) << 1) |
                      expand10(quant10(v2));
        keys[i] = (int)(m >> 20);          // top 10 bits
        atomicAdd(&hist[keys[i]], 1);
    }
    __syncthreads();

    int v = hist[tid];
    scanbuf[tid] = v;
    __syncthreads();
    for (int off = 1; off < 1024; off <<= 1) {   // Hillis-Steele inclusive
        int t = (tid >= off) ? scanbuf[tid - off] : 0;
        __syncthreads();
        scanbuf[tid] += t;
        __syncthreads();
    }
    offs[tid] = scanbuf[tid] - v;                // exclusive base
    __syncthreads();

#pragma unroll
    for (int i = 0; i < 4; ++i) {
        int p = tid + i * 1024;
        int pos = atomicAdd(&offs[keys[i]], 1);
        perm[b * N_ + pos] = p;
    }
}

// ===========================================================================
// Kernel 1: exact-match KNN (top-20, jax top_k semantics) + BN stats.
// Distance: fp32 EXPANSION form, bit-identical to np ref (verified r3-r5):
//   sq = (x*x + y*y) + z*z ;  d = (sq_i + sq_j) - 2*((xx+yy)+zz)
// Selection: 20 smallest u64 keys (sortable_fp32(d)<<32 | orig_j) — exact
// top_k with lowest-index tie-break, INDEPENDENT of scan order (keys are
// globally unique), so any candidate visit order is semantics-preserving.
//
// Round 6 change: ROTATED closest-first scan. Candidates staged in MORTON
// order (orig index bit-packed in .w; sq recomputed per candidate, +5 VALU).
// Each wave starts its quarter scan at the position nearest its own rows and
// wraps; prefill = first 20 of the rotated stream -> tight initial worst.
// r5 evidence: quarter-prefill gave random-order insert law (~78/lane spread
// uniformly -> 85% of groups took the ~120-instr insert body, 117
// instr/candidate measured). Rotation concentrates inserts in the first ~100
// positions; the tail is pure reject path (~25 instr/candidate).
// ===========================================================================
__global__ __launch_bounds__(512) void knn_quarter_kernel(
    const float* __restrict__ x, const int* __restrict__ perm,
    int* __restrict__ idx_out, double* __restrict__ stats)
{
    __shared__ __align__(16) char smem[65536];
    float4* pts = (float4*)smem;                         // {x,y,z,bitcast(j)}
    unsigned long long* scr = (unsigned long long*)smem; // merge-scratch view

    const int b    = blockIdx.y;
    const int tid  = threadIdx.x;
    const int wave = tid >> 6;
    const int lane = tid & 63;
    const int r    = wave >> 2;     // row-group 0..1
    const int q    = wave & 3;      // candidate quarter
    const float* xb = x + (size_t)b * N_ * CIN;

    // stage in MORTON order: pts[pos] = {x,y,z, bits(orig_j)}
    for (int p = tid; p < N_; p += 512) {
        int j = perm[b * N_ + p];                        // coalesced
        float v0 = xb[j * 3 + 0], v1 = xb[j * 3 + 1], v2 = xb[j * 3 + 2];
        pts[p] = make_float4(v0, v1, v2, __int_as_float(j));
    }
    __syncthreads();

    // rows: morton positions; orig row index from .w
    const int rowg = blockIdx.x * 128 + r * 64;          // wave's first row pos
    const float4 xf = pts[rowg + lane];
    const int jrow  = __float_as_int(xf.w);
    const float sqi = __fadd_rn(__fadd_rn(__fmul_rn(xf.x, xf.x),
                                          __fmul_rn(xf.y, xf.y)),
                                __fmul_rn(xf.z, xf.z));

    auto mkkey = [&](float4 p) -> unsigned long long {
        float sqj = __fadd_rn(__fadd_rn(__fmul_rn(p.x, p.x),
                                        __fmul_rn(p.y, p.y)),
                              __fmul_rn(p.z, p.z));
        float dot = __fadd_rn(__fadd_rn(__fmul_rn(xf.x, p.x),
                                        __fmul_rn(xf.y, p.y)),
                              __fmul_rn(xf.z, p.z));
        float d = __fsub_rn(__fadd_rn(sqi, sqj), __fmul_rn(2.0f, dot));
        unsigned u = __float_as_uint(d);
        unsigned s = u ^ (0x80000000u | (unsigned)((int)u >> 31));
        return ((unsigned long long)s << 32) |
               (unsigned)__float_as_int(p.w);
    };

    // rotated scan start (wave-uniform), aligned to group-of-4
    const int qbase = q * 1024;
    int srel = rowg - qbase;
    srel = srel < 0 ? 0 : (srel > 1023 ? 1023 : srel);
    srel &= ~3;

    unsigned long long bk[KNN];
    unsigned long long worst;

    // prefill: first 20 of the rotated stream (spatially closest -> tight worst)
#pragma unroll
    for (int k = 0; k < KNN; ++k)
        bk[k] = mkkey(pts[qbase + ((srel + k) & 1023)]);
    {
        unsigned long long w = 0;
#pragma unroll
        for (int k = 0; k < KNN; ++k) w = bk[k] > w ? bk[k] : w;
        worst = w;
    }

    // replace-by-value insert: keys unique -> exactly one slot matches worst
    auto insert = [&](unsigned long long key) {
        if (key < worst) {
            unsigned long long oldw = worst, nw = 0;
#pragma unroll
            for (int k = 0; k < KNN; ++k) {
                bk[k] = (bk[k] == oldw) ? key : bk[k];
                nw = bk[k] > nw ? bk[k] : nw;
            }
            worst = nw;
        }
    };

    for (int t = 20; t < 1024; t += 4) {
        int p0 = qbase + ((srel + t) & 1023);   // group never straddles wrap
        float4 a0 = pts[p0 + 0]; float4 a1 = pts[p0 + 1];
        float4 a2 = pts[p0 + 2]; float4 a3 = pts[p0 + 3];
        unsigned long long k0 = mkkey(a0);
        unsigned long long k1 = mkkey(a1);
        unsigned long long k2 = mkkey(a2);
        unsigned long long k3 = mkkey(a3);
        if ((k0 < worst) | (k1 < worst) | (k2 < worst) | (k3 < worst)) {
            insert(k0); insert(k1); insert(k2); insert(k3);
        }
    }
    __syncthreads();    // scans done; pts dead (xf in regs) -> scr valid

    // merge round A: q1 -> slot0, q3 -> slot1   (40KB <= 64KB)
    if (q & 1) {
        int base = ((r * 2 + (q >> 1)) * 64 + lane) * KNN;
#pragma unroll
        for (int k = 0; k < KNN; ++k) scr[base + k] = bk[k];
    }
    __syncthreads();
    if (!(q & 1)) {                 // q0 absorbs q1; q2 absorbs q3
        int base = ((r * 2 + (q >> 1)) * 64 + lane) * KNN;
#pragma unroll
        for (int k = 0; k < KNN; ++k) insert(scr[base + k]);
    }
    __syncthreads();
    // merge round B: q2 -> slot1; q0 absorbs
    if (q == 2) {
        int base = ((r * 2 + 1) * 64 + lane) * KNN;
#pragma unroll
        for (int k = 0; k < KNN; ++k) scr[base + k] = bk[k];
    }
    __syncthreads();
    if (q == 0) {
        int base = ((r * 2 + 1) * 64 + lane) * KNN;
#pragma unroll
        for (int k = 0; k < KNN; ++k) insert(scr[base + k]);

        const long long row = (long long)b * N_ + jrow;
        int bi[KNN];
#pragma unroll
        for (int k = 0; k < KNN; ++k) bi[k] = (int)(bk[k] & 0xFFFFFFFFull);
#pragma unroll
        for (int k = 0; k < KNN; ++k) idx_out[row * KNN + k] = bi[k];

        // --- BN statistics (neighbor coords from global; batch slab is hot)
        float acc[27];
#pragma unroll
        for (int t = 0; t < 27; ++t) acc[t] = 0.0f;
#pragma unroll
        for (int k = 0; k < KNN; ++k) {
            const float* pj = xb + bi[k] * 3;
            float e[6] = { xf.x, xf.y, xf.z,
                           pj[0] - xf.x, pj[1] - xf.y, pj[2] - xf.z };
            int t = 6;
#pragma unroll
            for (int a = 0; a < 6; ++a) {
                acc[a] += e[a];
#pragma unroll
                for (int bb = a; bb < 6; ++bb) acc[t++] += e[a] * e[bb];
            }
        }
#pragma unroll
        for (int t = 0; t < 27; ++t) {
            float v = acc[t];
            v += __shfl_down(v, 32); v += __shfl_down(v, 16);
            v += __shfl_down(v, 8);  v += __shfl_down(v, 4);
            v += __shfl_down(v, 2);  v += __shfl_down(v, 1);
            acc[t] = v;
        }
        if (lane == 0) {
#pragma unroll
            for (int t = 0; t < 27; ++t) atomicAdd(&stats[t], (double)acc[t]);
        }
    }
}

// ===========================================================================
// Kernel 2: fold stats -> per-channel scale/shift (fp64, 64 threads)
// ===========================================================================
__global__ void bn_prep_kernel(
    const double* __restrict__ stats,
    const float* __restrict__ w1, const float* __restrict__ b1,
    const float* __restrict__ gamma, const float* __restrict__ beta,
    float* __restrict__ scale_shift)
{
    const int c = threadIdx.x;
    double s[6], S[6][6];
#pragma unroll
    for (int a = 0; a < 6; ++a) s[a] = stats[a];
    int t = 6;
#pragma unroll
    for (int a = 0; a < 6; ++a)
#pragma unroll
        for (int bb = a; bb < 6; ++bb) { S[a][bb] = stats[t]; S[bb][a] = stats[t]; ++t; }

    const double M = (double)B_ * N_ * KNN;
    double wc[6];
#pragma unroll
    for (int j = 0; j < 6; ++j) wc[j] = (double)w1[j * COUT + c];
    const double b1c = (double)b1[c];

    double sw = 0.0;
#pragma unroll
    for (int j = 0; j < 6; ++j) sw += s[j] * wc[j];
    double mean = sw / M + b1c;

    double qq = 0.0;
#pragma unroll
    for (int a = 0; a < 6; ++a)
#pragma unroll
        for (int bb = 0; bb < 6; ++bb) qq += S[a][bb] * wc[a] * wc[bb];
    double ex2 = (qq + 2.0 * b1c * sw) / M + b1c * b1c;
    double var = ex2 - mean * mean;

    double sc = (double)gamma[c] / sqrt(var + (double)EPS_);
    double sh = (double)beta[c] - mean * sc;
    scale_shift[c]        = (float)sc;
    scale_shift[COUT + c] = (float)sh;
}

// ===========================================================================
// Kernel 3: fused edge-feature -> lin1 -> BN -> ReLU -> lin2 -> max over K.
// 8 rows per wave; rows processed in pairs packed [k][d][pair] in LDS.
// ===========================================================================
__global__ __launch_bounds__(256) void mlp_max_kernel(
    const float* __restrict__ x, const int* __restrict__ idx,
    const float* __restrict__ w1, const float* __restrict__ b1,
    const float* __restrict__ scale_shift,
    const float* __restrict__ w2, const float* __restrict__ b2,
    float* __restrict__ out)
{
    __shared__ __align__(16) float h2[4][KNN][COUT][2];   // 40 KB

    const int tid = threadIdx.x;
    const int wv  = tid >> 6;
    const int c   = tid & 63;

    float w1c[6];
#pragma unroll
    for (int j = 0; j < 6; ++j) w1c[j] = w1[j * COUT + c];
    const float b1c = b1[c];
    const float sc  = scale_shift[c];
    const float sh  = scale_shift[COUT + c];
    const float b2c = b2[c];
    float w2c[COUT];
#pragma unroll
    for (int d = 0; d < COUT; ++d) w2c[d] = w2[d * COUT + c];

    const int rowbase = (blockIdx.x * 4 + wv) * 8;

    for (int pair = 0; pair < 4; ++pair) {
        const int ra = rowbase + pair * 2;
#pragma unroll
        for (int rr = 0; rr < 2; ++rr) {
            const int row = ra + rr;
            const int b   = row >> 12;
            const float xi0 = x[row * 3 + 0];
            const float xi1 = x[row * 3 + 1];
            const float xi2 = x[row * 3 + 2];
#pragma unroll
            for (int k = 0; k < KNN; ++k) {
                int j = idx[row * KNN + k];               // wave-uniform
                const float* pj = x + ((size_t)b * N_ + j) * 3;
                float e3 = pj[0] - xi0, e4 = pj[1] - xi1, e5 = pj[2] - xi2;
                float h = b1c;
                h = fmaf(xi0, w1c[0], h); h = fmaf(xi1, w1c[1], h);
                h = fmaf(xi2, w1c[2], h); h = fmaf(e3,  w1c[3], h);
                h = fmaf(e4,  w1c[4], h); h = fmaf(e5,  w1c[5], h);
                h = fmaf(h, sc, sh);
                h2[wv][k][c][rr] = fmaxf(h, 0.0f);        // 2-way bank alias: free
            }
        }
        __syncthreads();   // uniform across the block's 4 waves

        float mxa = -INFINITY, mxb = -INFINITY;
        for (int k = 0; k < KNN; ++k) {
            float aa = b2c, ab = b2c;
#pragma unroll
            for (int d2 = 0; d2 < COUT / 2; ++d2) {
                float4 hv = *(const float4*)&h2[wv][k][d2 * 2][0]; // broadcast
                aa = fmaf(hv.x, w2c[d2 * 2 + 0], aa);
                ab = fmaf(hv.y, w2c[d2 * 2 + 0], ab);
                aa = fmaf(hv.z, w2c[d2 * 2 + 1], aa);
                ab = fmaf(hv.w, w2c[d2 * 2 + 1], ab);
            }
            mxa = fmaxf(mxa, aa); mxb = fmaxf(mxb, ab);
        }
        out[(size_t)ra * COUT + c]       = mxa;
        out[(size_t)(ra + 1) * COUT + c] = mxb;
        __syncthreads();   // protect h2 reuse next pair
    }
}

// ===========================================================================
extern "C" void kernel_launch(void* const* d_in, const int* in_sizes, int n_in,
                              void* d_out, int out_size, void* d_ws, size_t ws_size,
                              hipStream_t stream)
{
    const float* x     = (const float*)d_in[0];
    const float* w1    = (const float*)d_in[2];
    const float* b1    = (const float*)d_in[3];
    const float* gamma = (const float*)d_in[4];
    const float* beta  = (const float*)d_in[5];
    const float* w2    = (const float*)d_in[6];
    const float* b2    = (const float*)d_in[7];
    float* out = (float*)d_out;

    char*   ws          = (char*)d_ws;
    double* stats       = (double*)ws;
    float*  scale_shift = (float*)(ws + 256);
    int*    idx         = (int*)(ws + 1024);
    int*    perm        = (int*)(ws + 1024 + (size_t)B_ * N_ * KNN * 4);

    hipMemsetAsync(stats, 0, 27 * sizeof(double), stream);
    morton_bucket_kernel<<<B_, 1024, 0, stream>>>(x, perm);
    knn_quarter_kernel<<<dim3(32, 16), 512, 0, stream>>>(x, perm, idx, stats);
    bn_prep_kernel<<<1, COUT, 0, stream>>>(stats, w1, b1, gamma, beta, scale_shift);
    mlp_max_kernel<<<(B_ * N_) / 32, 256, 0, stream>>>(x, idx, w1, b1, scale_shift,
                                                       w2, b2, out);
}

// Round 7
// 913.079 us; speedup vs baseline: 1.2284x; 1.2284x over previous
//
#include <hip/hip_runtime.h>
#include <math.h>
#include <float.h>

#define B_   16
#define N_   4096
#define CIN  3
#define COUT 64
#define KNN  20
#define EPS_ 1e-5

// ---------------------------------------------------------------------------
// Workspace layout:
//   [0,   216): double stats[27]    (Sum e[6], Sum e e^T upper-tri[21])
//   [256, 768): float scale[64], shift[64]
//   [1024, 1024 + B*N*KNN*4): int idx[B*N*KNN]           (5242880 B)
//   [5243904, +B*N*4): int perm[B*N]  (Morton row order)  (262144 B)
// ---------------------------------------------------------------------------

__device__ __forceinline__ unsigned expand10(unsigned v) {
    v = (v | (v << 16)) & 0x030000FFu;
    v = (v | (v << 8))  & 0x0300F00Fu;
    v = (v | (v << 4))  & 0x030C30C3u;
    v = (v | (v << 2))  & 0x09249249u;
    return v;
}
__device__ __forceinline__ unsigned quant10(float v) {
    int q = (int)((v + 4.0f) * 128.0f);
    return (unsigned)min(1023, max(0, q));
}

// ===========================================================================
// Kernel 0: per-batch Morton COUNTING sort (1024 buckets = top 10 morton
// bits). PERFORMANCE ONLY: any permutation is correctness-neutral.
// ===========================================================================
__global__ __launch_bounds__(1024) void morton_bucket_kernel(
    const float* __restrict__ x, int* __restrict__ perm)
{
    __shared__ int hist[1024];
    __shared__ int scanbuf[1024];
    __shared__ int offs[1024];
    const int b = blockIdx.x, tid = threadIdx.x;
    const float* xb = x + (size_t)b * N_ * CIN;

    hist[tid] = 0;
    __syncthreads();

    int keys[4];
#pragma unroll
    for (int i = 0; i < 4; ++i) {
        int p = tid + i * 1024;
        float v0 = xb[p * 3 + 0], v1 = xb[p * 3 + 1], v2 = xb[p * 3 + 2];
        unsigned m = (expand10(quant10(v0)) << 2) |
                     (expand10(quant10(v1)) << 1) |
                      expand10(quant10(v2));
        keys[i] = (int)(m >> 20);          // top 10 bits
        atomicAdd(&hist[keys[i]], 1);
    }
    __syncthreads();

    int v = hist[tid];
    scanbuf[tid] = v;
    __syncthreads();
    for (int off = 1; off < 1024; off <<= 1) {   // Hillis-Steele inclusive
        int t = (tid >= off) ? scanbuf[tid - off] : 0;
        __syncthreads();
        scanbuf[tid] += t;
        __syncthreads();
    }
    offs[tid] = scanbuf[tid] - v;                // exclusive base
    __syncthreads();

#pragma unroll
    for (int i = 0; i < 4; ++i) {
        int p = tid + i * 1024;
        int pos = atomicAdd(&offs[keys[i]], 1);
        perm[b * N_ + pos] = p;
    }
}

// ===========================================================================
// Kernel 1: exact-match KNN (top-20, jax top_k semantics) + BN stats.
// Distance: fp32 EXPANSION form, bit-identical to np ref (verified r3-r6).
// Selection: 20 smallest u64 keys (sortable_fp32(d)<<32 | orig_j) — exact
// top_k with lowest-index tie-break, INDEPENDENT of candidate visit order
// (keys globally unique), so any visit order is semantics-preserving.
//
// Round 7: ball prefill + SHUFFLED scan.
//   r5 (random order, random prefill): 117 instr/candidate — inserts follow
//     the 20/t random law, spread through the whole scan.
//   r6 (morton order, ball prefill): REGRESSED — Z-curve scan re-approaches
//     the query repeatedly (octant transitions) -> insert bursts, worse
//     wave-union trigger rate + imbalance (VALUBusy 64->50).
//   r7: keep the tight ball prefill (20 morton-adjacent candidates -> tight
//     initial worst), visit the rest via v=(t*509) mod 1024 stride shuffle
//     (odd multiplier = bijection, spatially random). Insert rate starts low
//     AND decays. Shuffle offsets are scalar-uniform (SGPR math, free);
//     prefill positions are skipped via a uniform sentinel so each candidate
//     is visited exactly once.
// ===========================================================================
__global__ __launch_bounds__(512) void knn_quarter_kernel(
    const float* __restrict__ x, const int* __restrict__ perm,
    int* __restrict__ idx_out, double* __restrict__ stats)
{
    __shared__ __align__(16) char smem[65536];
    float4* pts = (float4*)smem;                         // {x,y,z,bitcast(j)}
    unsigned long long* scr = (unsigned long long*)smem; // merge-scratch view

    const int b    = blockIdx.y;
    const int tid  = threadIdx.x;
    const int wave = tid >> 6;
    const int lane = tid & 63;
    const int r    = wave >> 2;     // row-group 0..1
    const int q    = wave & 3;      // candidate quarter
    const float* xb = x + (size_t)b * N_ * CIN;

    // stage in MORTON order: pts[pos] = {x,y,z, bits(orig_j)}
    for (int p = tid; p < N_; p += 512) {
        int j = perm[b * N_ + p];                        // coalesced
        float v0 = xb[j * 3 + 0], v1 = xb[j * 3 + 1], v2 = xb[j * 3 + 2];
        pts[p] = make_float4(v0, v1, v2, __int_as_float(j));
    }
    __syncthreads();

    // rows: morton positions; orig row index from .w
    const int rowg = blockIdx.x * 128 + r * 64;          // wave's first row pos
    const float4 xf = pts[rowg + lane];
    const int jrow  = __float_as_int(xf.w);
    const float sqi = __fadd_rn(__fadd_rn(__fmul_rn(xf.x, xf.x),
                                          __fmul_rn(xf.y, xf.y)),
                                __fmul_rn(xf.z, xf.z));

    auto mkkey = [&](float4 p) -> unsigned long long {
        float sqj = __fadd_rn(__fadd_rn(__fmul_rn(p.x, p.x),
                                        __fmul_rn(p.y, p.y)),
                              __fmul_rn(p.z, p.z));
        float dot = __fadd_rn(__fadd_rn(__fmul_rn(xf.x, p.x),
                                        __fmul_rn(xf.y, p.y)),
                              __fmul_rn(xf.z, p.z));
        float d = __fsub_rn(__fadd_rn(sqi, sqj), __fmul_rn(2.0f, dot));
        unsigned u = __float_as_uint(d);
        unsigned s = u ^ (0x80000000u | (unsigned)((int)u >> 31));
        return ((unsigned long long)s << 32) |
               (unsigned)__float_as_int(p.w);
    };

    // ball prefill anchor: quarter position nearest the wave's rows
    const int qbase = q * 1024;
    int srel = rowg - qbase;
    srel = srel < 0 ? 0 : (srel > 1023 ? 1023 : srel);

    unsigned long long bk[KNN];
    unsigned long long worst;

    // prefill: 20 morton-adjacent candidates (positions srel..srel+19, wrap)
#pragma unroll
    for (int k = 0; k < KNN; ++k)
        bk[k] = mkkey(pts[qbase + ((srel + k) & 1023)]);
    {
        unsigned long long w = 0;
#pragma unroll
        for (int k = 0; k < KNN; ++k) w = bk[k] > w ? bk[k] : w;
        worst = w;
    }

    // replace-by-value insert: keys unique -> exactly one slot matches worst
    auto insert = [&](unsigned long long key) {
        if (key < worst) {
            unsigned long long oldw = worst, nw = 0;
#pragma unroll
            for (int k = 0; k < KNN; ++k) {
                bk[k] = (bk[k] == oldw) ? key : bk[k];
                nw = bk[k] > nw ? bk[k] : nw;
            }
            worst = nw;
        }
    };

    // shuffled scan: v = (t*509) & 1023 is a bijection on [0,1024);
    // v<20 are the prefill positions -> masked with sentinel (never inserts).
    for (int t = 0; t < 1024; t += 4) {
        int v0 = ((t + 0) * 509) & 1023;     // scalar-uniform (SGPR math)
        int v1 = ((t + 1) * 509) & 1023;
        int v2 = ((t + 2) * 509) & 1023;
        int v3 = ((t + 3) * 509) & 1023;
        float4 a0 = pts[qbase + ((srel + v0) & 1023)];
        float4 a1 = pts[qbase + ((srel + v1) & 1023)];
        float4 a2 = pts[qbase + ((srel + v2) & 1023)];
        float4 a3 = pts[qbase + ((srel + v3) & 1023)];
        unsigned long long k0 = (v0 < 20) ? ~0ull : mkkey(a0);
        unsigned long long k1 = (v1 < 20) ? ~0ull : mkkey(a1);
        unsigned long long k2 = (v2 < 20) ? ~0ull : mkkey(a2);
        unsigned long long k3 = (v3 < 20) ? ~0ull : mkkey(a3);
        if ((k0 < worst) | (k1 < worst) | (k2 < worst) | (k3 < worst)) {
            insert(k0); insert(k1); insert(k2); insert(k3);
        }
    }
    __syncthreads();    // scans done; pts dead (xf in regs) -> scr valid

    // merge round A: q1 -> slot0, q3 -> slot1   (40KB <= 64KB)
    if (q & 1) {
        int base = ((r * 2 + (q >> 1)) * 64 + lane) * KNN;
#pragma unroll
        for (int k = 0; k < KNN; ++k) scr[base + k] = bk[k];
    }
    __syncthreads();
    if (!(q & 1)) {                 // q0 absorbs q1; q2 absorbs q3
        int base = ((r * 2 + (q >> 1)) * 64 + lane) * KNN;
#pragma unroll
        for (int k = 0; k < KNN; ++k) insert(scr[base + k]);
    }
    __syncthreads();
    // merge round B: q2 -> slot1; q0 absorbs
    if (q == 2) {
        int base = ((r * 2 + 1) * 64 + lane) * KNN;
#pragma unroll
        for (int k = 0; k < KNN; ++k) scr[base + k] = bk[k];
    }
    __syncthreads();
    if (q == 0) {
        int base = ((r * 2 + 1) * 64 + lane) * KNN;
#pragma unroll
        for (int k = 0; k < KNN; ++k) insert(scr[base + k]);

        const long long row = (long long)b * N_ + jrow;
        int bi[KNN];
#pragma unroll
        for (int k = 0; k < KNN; ++k) bi[k] = (int)(bk[k] & 0xFFFFFFFFull);
#pragma unroll
        for (int k = 0; k < KNN; ++k) idx_out[row * KNN + k] = bi[k];

        // --- BN statistics (neighbor coords from global; batch slab is hot)
        float acc[27];
#pragma unroll
        for (int t = 0; t < 27; ++t) acc[t] = 0.0f;
#pragma unroll
        for (int k = 0; k < KNN; ++k) {
            const float* pj = xb + bi[k] * 3;
            float e[6] = { xf.x, xf.y, xf.z,
                           pj[0] - xf.x, pj[1] - xf.y, pj[2] - xf.z };
            int t = 6;
#pragma unroll
            for (int a = 0; a < 6; ++a) {
                acc[a] += e[a];
#pragma unroll
                for (int bb = a; bb < 6; ++bb) acc[t++] += e[a] * e[bb];
            }
        }
#pragma unroll
        for (int t = 0; t < 27; ++t) {
            float v = acc[t];
            v += __shfl_down(v, 32); v += __shfl_down(v, 16);
            v += __shfl_down(v, 8);  v += __shfl_down(v, 4);
            v += __shfl_down(v, 2);  v += __shfl_down(v, 1);
            acc[t] = v;
        }
        if (lane == 0) {
#pragma unroll
            for (int t = 0; t < 27; ++t) atomicAdd(&stats[t], (double)acc[t]);
        }
    }
}

// ===========================================================================
// Kernel 2: fold stats -> per-channel scale/shift (fp64, 64 threads)
// ===========================================================================
__global__ void bn_prep_kernel(
    const double* __restrict__ stats,
    const float* __restrict__ w1, const float* __restrict__ b1,
    const float* __restrict__ gamma, const float* __restrict__ beta,
    float* __restrict__ scale_shift)
{
    const int c = threadIdx.x;
    double s[6], S[6][6];
#pragma unroll
    for (int a = 0; a < 6; ++a) s[a] = stats[a];
    int t = 6;
#pragma unroll
    for (int a = 0; a < 6; ++a)
#pragma unroll
        for (int bb = a; bb < 6; ++bb) { S[a][bb] = stats[t]; S[bb][a] = stats[t]; ++t; }

    const double M = (double)B_ * N_ * KNN;
    double wc[6];
#pragma unroll
    for (int j = 0; j < 6; ++j) wc[j] = (double)w1[j * COUT + c];
    const double b1c = (double)b1[c];

    double sw = 0.0;
#pragma unroll
    for (int j = 0; j < 6; ++j) sw += s[j] * wc[j];
    double mean = sw / M + b1c;

    double qq = 0.0;
#pragma unroll
    for (int a = 0; a < 6; ++a)
#pragma unroll
        for (int bb = 0; bb < 6; ++bb) qq += S[a][bb] * wc[a] * wc[bb];
    double ex2 = (qq + 2.0 * b1c * sw) / M + b1c * b1c;
    double var = ex2 - mean * mean;

    double sc = (double)gamma[c] / sqrt(var + (double)EPS_);
    double sh = (double)beta[c] - mean * sc;
    scale_shift[c]        = (float)sc;
    scale_shift[COUT + c] = (float)sh;
}

// ===========================================================================
// Kernel 3: fused edge-feature -> lin1 -> BN -> ReLU -> lin2 -> max over K.
// 8 rows per wave; rows processed in pairs packed [k][d][pair] in LDS.
// ===========================================================================
__global__ __launch_bounds__(256) void mlp_max_kernel(
    const float* __restrict__ x, const int* __restrict__ idx,
    const float* __restrict__ w1, const float* __restrict__ b1,
    const float* __restrict__ scale_shift,
    const float* __restrict__ w2, const float* __restrict__ b2,
    float* __restrict__ out)
{
    __shared__ __align__(16) float h2[4][KNN][COUT][2];   // 40 KB

    const int tid = threadIdx.x;
    const int wv  = tid >> 6;
    const int c   = tid & 63;

    float w1c[6];
#pragma unroll
    for (int j = 0; j < 6; ++j) w1c[j] = w1[j * COUT + c];
    const float b1c = b1[c];
    const float sc  = scale_shift[c];
    const float sh  = scale_shift[COUT + c];
    const float b2c = b2[c];
    float w2c[COUT];
#pragma unroll
    for (int d = 0; d < COUT; ++d) w2c[d] = w2[d * COUT + c];

    const int rowbase = (blockIdx.x * 4 + wv) * 8;

    for (int pair = 0; pair < 4; ++pair) {
        const int ra = rowbase + pair * 2;
#pragma unroll
        for (int rr = 0; rr < 2; ++rr) {
            const int row = ra + rr;
            const int b   = row >> 12;
            const float xi0 = x[row * 3 + 0];
            const float xi1 = x[row * 3 + 1];
            const float xi2 = x[row * 3 + 2];
#pragma unroll
            for (int k = 0; k < KNN; ++k) {
                int j = idx[row * KNN + k];               // wave-uniform
                const float* pj = x + ((size_t)b * N_ + j) * 3;
                float e3 = pj[0] - xi0, e4 = pj[1] - xi1, e5 = pj[2] - xi2;
                float h = b1c;
                h = fmaf(xi0, w1c[0], h); h = fmaf(xi1, w1c[1], h);
                h = fmaf(xi2, w1c[2], h); h = fmaf(e3,  w1c[3], h);
                h = fmaf(e4,  w1c[4], h); h = fmaf(e5,  w1c[5], h);
                h = fmaf(h, sc, sh);
                h2[wv][k][c][rr] = fmaxf(h, 0.0f);        // 2-way bank alias: free
            }
        }
        __syncthreads();   // uniform across the block's 4 waves

        float mxa = -INFINITY, mxb = -INFINITY;
        for (int k = 0; k < KNN; ++k) {
            float aa = b2c, ab = b2c;
#pragma unroll
            for (int d2 = 0; d2 < COUT / 2; ++d2) {
                float4 hv = *(const float4*)&h2[wv][k][d2 * 2][0]; // broadcast
                aa = fmaf(hv.x, w2c[d2 * 2 + 0], aa);
                ab = fmaf(hv.y, w2c[d2 * 2 + 0], ab);
                aa = fmaf(hv.z, w2c[d2 * 2 + 1], aa);
                ab = fmaf(hv.w, w2c[d2 * 2 + 1], ab);
            }
            mxa = fmaxf(mxa, aa); mxb = fmaxf(mxb, ab);
        }
        out[(size_t)ra * COUT + c]       = mxa;
        out[(size_t)(ra + 1) * COUT + c] = mxb;
        __syncthreads();   // protect h2 reuse next pair
    }
}

// ===========================================================================
extern "C" void kernel_launch(void* const* d_in, const int* in_sizes, int n_in,
                              void* d_out, int out_size, void* d_ws, size_t ws_size,
                              hipStream_t stream)
{
    const float* x     = (const float*)d_in[0];
    const float* w1    = (const float*)d_in[2];
    const float* b1    = (const float*)d_in[3];
    const float* gamma = (const float*)d_in[4];
    const float* beta  = (const float*)d_in[5];
    const float* w2    = (const float*)d_in[6];
    const float* b2    = (const float*)d_in[7];
    float* out = (float*)d_out;

    char*   ws          = (char*)d_ws;
    double* stats       = (double*)ws;
    float*  scale_shift = (float*)(ws + 256);
    int*    idx         = (int*)(ws + 1024);
    int*    perm        = (int*)(ws + 1024 + (size_t)B_ * N_ * KNN * 4);

    hipMemsetAsync(stats, 0, 27 * sizeof(double), stream);
    morton_bucket_kernel<<<B_, 1024, 0, stream>>>(x, perm);
    knn_quarter_kernel<<<dim3(32, 16), 512, 0, stream>>>(x, perm, idx, stats);
    bn_prep_kernel<<<1, COUT, 0, stream>>>(stats, w1, b1, gamma, beta, scale_shift);
    mlp_max_kernel<<<(B_ * N_) / 32, 256, 0, stream>>>(x, idx, w1, b1, scale_shift,
                                                       w2, b2, out);
}